// Round 1
// baseline (2011.544 us; speedup 1.0000x reference)
//
#include <hip/hip_runtime.h>

// MHA block: out = (softmax(QK^T/sqrt(dk)) V) @ Wo^T, Q/K/V = x @ W^T
// B=2, S=2048, HIDDEN=4096, HEADS=32, DK=128. All fp32 in/out, bf16 MFMA inside.

typedef __attribute__((ext_vector_type(8))) short bf16x8;
typedef __attribute__((ext_vector_type(4))) float f32x4;

__device__ __forceinline__ unsigned short f2bf(float f) {
  unsigned int u = __float_as_uint(f);
  unsigned int r = (u + 0x7fffu + ((u >> 16) & 1u)) >> 16;
  return (unsigned short)r;
}

__device__ __forceinline__ void gload_lds16(const void* g, void* l) {
  __builtin_amdgcn_global_load_lds(
      (__attribute__((address_space(1))) void*)(g),
      (__attribute__((address_space(3))) void*)(l), 16, 0, 0);
}

// ---------------- fp32 -> bf16 convert (vectorized) ----------------
__global__ void mha_f32_to_bf16(const float* __restrict__ in,
                                unsigned short* __restrict__ out, int n4) {
  int i = blockIdx.x * 256 + threadIdx.x;
  if (i >= n4) return;
  float4 v = reinterpret_cast<const float4*>(in)[i];
  ushort4 o;
  o.x = f2bf(v.x); o.y = f2bf(v.y); o.z = f2bf(v.z); o.w = f2bf(v.w);
  reinterpret_cast<ushort4*>(out)[i] = o;
}

// ---------------- bf16 bt-GEMM: C[M,N] = A[M,K] @ B[N,K]^T ----------------
// m97 structure: 128x128 tile, BK=32, 4 waves (2x2), each wave 64x64 = 4x4 MFMA frags.
template<int BF16OUT>
__global__ __launch_bounds__(256) void mha_gemm_bt(
    const unsigned short* __restrict__ A,
    const unsigned short* __restrict__ B,
    void* __restrict__ Cout, int M, int N, int K) {
  __shared__ __align__(16) unsigned short As[128 * 32];
  __shared__ __align__(16) unsigned short Bs[128 * 32];
  const int tid = threadIdx.x;
  const int lane = tid & 63;
  const int wid = tid >> 6;
  const int wm = wid >> 1, wn = wid & 1;
  const int bm = blockIdx.x, bn = blockIdx.y;

  const unsigned short* Ab = A + (size_t)bm * 128 * K;
  const unsigned short* Bb = B + (size_t)bn * 128 * K;

  // staging map: chunk c (1KB = 16 rows of 32 bf16): rows c*16..+15
  // lane i covers byte c*1024 + i*16 -> row c*16 + i/4, k = (i&3)*8
  const int ca = wid * 2;
  const int rowA0 = ca * 16 + (lane >> 2);
  const int kcol = (lane & 3) * 8;

  f32x4 acc[4][4] = {};

  for (int k0 = 0; k0 < K; k0 += 32) {
    __syncthreads();
    gload_lds16(Ab + (size_t)rowA0 * K + k0 + kcol, (char*)As + ca * 1024);
    gload_lds16(Ab + (size_t)(rowA0 + 16) * K + k0 + kcol, (char*)As + ca * 1024 + 1024);
    gload_lds16(Bb + (size_t)rowA0 * K + k0 + kcol, (char*)Bs + ca * 1024);
    gload_lds16(Bb + (size_t)(rowA0 + 16) * K + k0 + kcol, (char*)Bs + ca * 1024 + 1024);
    __syncthreads();
    bf16x8 a[4], b[4];
#pragma unroll
    for (int i = 0; i < 4; ++i) {
      a[i] = *reinterpret_cast<const bf16x8*>(&As[(wm * 64 + i * 16 + (lane & 15)) * 32 + (lane >> 4) * 8]);
      b[i] = *reinterpret_cast<const bf16x8*>(&Bs[(wn * 64 + i * 16 + (lane & 15)) * 32 + (lane >> 4) * 8]);
    }
#pragma unroll
    for (int i = 0; i < 4; ++i)
#pragma unroll
      for (int j = 0; j < 4; ++j)
        acc[i][j] = __builtin_amdgcn_mfma_f32_16x16x32_bf16(a[i], b[j], acc[i][j], 0, 0, 0);
  }

  // C/D layout: col = lane&15, row = (lane>>4)*4 + r  [m89 verified]
  const int r0 = bm * 128 + wm * 64 + (lane >> 4) * 4;
  const int c0 = bn * 128 + wn * 64 + (lane & 15);
#pragma unroll
  for (int i = 0; i < 4; ++i)
#pragma unroll
    for (int j = 0; j < 4; ++j)
#pragma unroll
      for (int r = 0; r < 4; ++r) {
        size_t idx = (size_t)(r0 + i * 16 + r) * N + (c0 + j * 16);
        if (BF16OUT) ((unsigned short*)Cout)[idx] = f2bf(acc[i][j][r]);
        else ((float*)Cout)[idx] = acc[i][j][r];
      }
}

// ---------------- flash attention ----------------
// Q/K/V in [B*S, 4096] bf16 layout (head h = cols h*128..h*128+127).
// Block: 256 thr = 4 waves; each wave owns 16 q-rows; QB=64 rows/block.
// grid = (S/64, B*HEADS)
__global__ __launch_bounds__(256) void mha_flash(
    const unsigned short* __restrict__ Q, const unsigned short* __restrict__ K,
    const unsigned short* __restrict__ V, unsigned short* __restrict__ O) {
  const int S = 2048, HID = 4096, DK = 128;
  const int bh = blockIdx.y;
  const int b = bh >> 5, h = bh & 31;
  const int q0 = blockIdx.x * 64;
  const int tid = threadIdx.x, lane = tid & 63, w = tid >> 6;

  __shared__ __align__(16) unsigned short Ks[64 * 128];   // [krow][d]
  __shared__ __align__(16) unsigned short Vt[128 * 64];   // [d][krow] (transposed)
  __shared__ __align__(16) unsigned short Ps[4][16 * 64]; // per-wave P tile [q][k]

  const unsigned short* qbase = Q + (size_t)b * S * HID + h * DK;
  const unsigned short* kbase = K + (size_t)b * S * HID + h * DK;
  const unsigned short* vbase = V + (size_t)b * S * HID + h * DK;

  // Q fragments in registers: A-operand, row = lane&15 (local), k = ks*32+(lane>>4)*8
  bf16x8 qf[4];
  {
    const int qrow = q0 + w * 16 + (lane & 15);
#pragma unroll
    for (int ks = 0; ks < 4; ++ks)
      qf[ks] = *reinterpret_cast<const bf16x8*>(qbase + (size_t)qrow * HID + ks * 32 + (lane >> 4) * 8);
  }

  float mrow[4] = {-INFINITY, -INFINITY, -INFINITY, -INFINITY};
  float lrow[4] = {0.f, 0.f, 0.f, 0.f};
  f32x4 o[8] = {};
  const float scale = 0.08838834764831843f; // 1/sqrt(128)

  for (int kt = 0; kt < S / 64; ++kt) {
    __syncthreads(); // prev tile's reads done before overwrite
    // stage K [64][128] via global_load_lds (16 chunks of 1KB)
#pragma unroll
    for (int j = 0; j < 4; ++j) {
      int c = j * 4 + w;
      int row = c * 4 + (lane >> 4);
      int d8 = (lane & 15) * 8;
      gload_lds16(kbase + (size_t)(kt * 64 + row) * HID + d8, (char*)Ks + c * 1024);
    }
    // stage V transposed (reg path: coalesced 16B reads, scalar LDS writes)
#pragma unroll
    for (int j = 0; j < 4; ++j) {
      int n = j * 256 + tid;
      int s = n >> 4;
      int d0 = (n & 15) * 8;
      bf16x8 vv = *reinterpret_cast<const bf16x8*>(vbase + (size_t)(kt * 64 + s) * HID + d0);
#pragma unroll
      for (int i = 0; i < 8; ++i)
        Vt[(d0 + i) * 64 + s] = (unsigned short)vv[i];
    }
    __syncthreads(); // staging visible (vmcnt+lgkm drained)

    // S_tile[16q][64k] = Q @ K^T  (per wave)
    f32x4 sacc[4] = {};
#pragma unroll
    for (int cf = 0; cf < 4; ++cf)
#pragma unroll
      for (int ks = 0; ks < 4; ++ks) {
        bf16x8 kf = *reinterpret_cast<const bf16x8*>(&Ks[(cf * 16 + (lane & 15)) * 128 + ks * 32 + (lane >> 4) * 8]);
        sacc[cf] = __builtin_amdgcn_mfma_f32_16x16x32_bf16(qf[ks], kf, sacc[cf], 0, 0, 0);
      }
#pragma unroll
    for (int cf = 0; cf < 4; ++cf)
#pragma unroll
      for (int r = 0; r < 4; ++r)
        sacc[cf][r] *= scale;

    // online softmax; row = (lane>>4)*4 + r, cols spread over 16 lanes x 4 frags
#pragma unroll
    for (int r = 0; r < 4; ++r) {
      float mx = fmaxf(fmaxf(sacc[0][r], sacc[1][r]), fmaxf(sacc[2][r], sacc[3][r]));
#pragma unroll
      for (int d = 1; d < 16; d <<= 1) mx = fmaxf(mx, __shfl_xor(mx, d, 64));
      float mn = fmaxf(mrow[r], mx);
      float sc = __expf(mrow[r] - mn);
      float rs = 0.f;
#pragma unroll
      for (int cf = 0; cf < 4; ++cf) {
        float p = __expf(sacc[cf][r] - mn);
        sacc[cf][r] = p;
        rs += p;
      }
#pragma unroll
      for (int d = 1; d < 16; d <<= 1) rs += __shfl_xor(rs, d, 64);
      mrow[r] = mn;
      lrow[r] = lrow[r] * sc + rs;
#pragma unroll
      for (int df = 0; df < 8; ++df) o[df][r] *= sc;
    }

    // P -> LDS (bf16) for fragment relayout (per-wave region, no barrier needed)
#pragma unroll
    for (int cf = 0; cf < 4; ++cf)
#pragma unroll
      for (int r = 0; r < 4; ++r)
        Ps[w][((lane >> 4) * 4 + r) * 64 + cf * 16 + (lane & 15)] = f2bf(sacc[cf][r]);

    // O[16q][128d] += P @ V
#pragma unroll
    for (int kk = 0; kk < 2; ++kk) {
      bf16x8 pf = *reinterpret_cast<const bf16x8*>(&Ps[w][(lane & 15) * 64 + kk * 32 + (lane >> 4) * 8]);
#pragma unroll
      for (int df = 0; df < 8; ++df) {
        bf16x8 vf = *reinterpret_cast<const bf16x8*>(&Vt[(df * 16 + (lane & 15)) * 64 + kk * 32 + (lane >> 4) * 8]);
        o[df] = __builtin_amdgcn_mfma_f32_16x16x32_bf16(pf, vf, o[df], 0, 0, 0);
      }
    }
  }

  // epilogue: O /= l, write bf16 to attn-out [B*S][4096]
#pragma unroll
  for (int r = 0; r < 4; ++r) {
    float inv = 1.f / lrow[r];
    int row = q0 + w * 16 + (lane >> 4) * 4 + r;
    unsigned short* ob = O + (size_t)(b * S + row) * HID + h * DK;
#pragma unroll
    for (int df = 0; df < 8; ++df)
      ob[df * 16 + (lane & 15)] = f2bf(o[df][r] * inv);
  }
}

// ---------------- launch ----------------
extern "C" void kernel_launch(void* const* d_in, const int* in_sizes, int n_in,
                              void* d_out, int out_size, void* d_ws, size_t ws_size,
                              hipStream_t stream) {
  const float* x = (const float*)d_in[0];
  const float* wq = (const float*)d_in[1];
  const float* wk = (const float*)d_in[2];
  const float* wv = (const float*)d_in[3];
  const float* wo = (const float*)d_in[4];
  float* out = (float*)d_out;

  const size_t E = 16777216; // 4096*4096
  // ws layout (bf16): [xb | wb | qb | kb | vb] = 5 * 32 MB = 160 MB
  unsigned short* xb = (unsigned short*)d_ws;
  unsigned short* wb = xb + E;
  unsigned short* qb = xb + 2 * E;
  unsigned short* kb = xb + 3 * E;
  unsigned short* vb = xb + 4 * E;
  unsigned short* ab = xb; // attn-out reuses xb (x dead after V projection)

  dim3 cb(256);
  dim3 cg((unsigned)(E / 4 / 256)); // 16384 blocks
  dim3 gg(32, 32), gb(256);
  dim3 fg(32, 64), fb(256);

  mha_f32_to_bf16<<<cg, cb, 0, stream>>>(x, xb, (int)(E / 4));
  mha_f32_to_bf16<<<cg, cb, 0, stream>>>(wq, wb, (int)(E / 4));
  mha_gemm_bt<1><<<gg, gb, 0, stream>>>(xb, wb, (void*)qb, 4096, 4096, 4096);
  mha_f32_to_bf16<<<cg, cb, 0, stream>>>(wk, wb, (int)(E / 4));
  mha_gemm_bt<1><<<gg, gb, 0, stream>>>(xb, wb, (void*)kb, 4096, 4096, 4096);
  mha_f32_to_bf16<<<cg, cb, 0, stream>>>(wv, wb, (int)(E / 4));
  mha_gemm_bt<1><<<gg, gb, 0, stream>>>(xb, wb, (void*)vb, 4096, 4096, 4096);
  mha_flash<<<fg, fb, 0, stream>>>(qb, kb, vb, ab);
  mha_f32_to_bf16<<<cg, cb, 0, stream>>>(wo, wb, (int)(E / 4));
  mha_gemm_bt<0><<<gg, gb, 0, stream>>>(ab, wb, (void*)out, 4096, 4096, 4096);
}